// Round 17
// baseline (210.961 us; speedup 1.0000x reference)
//
#include <hip/hip_runtime.h>
#include <hip/hip_bf16.h>

// GCN. CSR via 2-pass LDS bucket sort; tables prescaled by dinv[src] (csr = 4 B/edge).
// Layer-2 gather SPLIT into two 4 MB half-channel fp8 tables, one pass each —
// a 4 MB table is L2-resident per XCD (agg_x evidence: same edge count runs
// 3x faster on a 4 MB table than 8 MB). h1 LDS-only (fused w1+w2).
// Pads -> dedicated zero row N_NODES. fp32 accumulate everywhere.

#define N_NODES 131072
#define N_EDGES 2097152
#define N_GRAPHS 2048
#define IN_CH 12
#define HID 64
#define OUT_CH 4
#define NBUCK 512          // buckets of 256 dst nodes
#define CHUNK 8192         // edges per bucket_kernel block
#define STRIDE 4608        // staging capacity per bucket (mean 4096, sd 64)
#define CSR_STRIDE 5120    // csr capacity per bucket (padded mean ~4500)
#define CAP 5120           // build_kernel LDS image capacity (20.5 KB, int)

typedef float f32x2 __attribute__((ext_vector_type(2)));

__device__ __forceinline__ unsigned short f2bf(float f) {
    unsigned u = __float_as_uint(f);
    return (unsigned short)((u + 0x7fffu + ((u >> 16) & 1u)) >> 16);  // RNE
}
__device__ __forceinline__ unsigned pack2bf(float lo, float hi) {
    return (unsigned)f2bf(lo) | ((unsigned)f2bf(hi) << 16);
}
__device__ __forceinline__ float bflo(unsigned v) { return __uint_as_float(v << 16); }
__device__ __forceinline__ float bfhi(unsigned v) { return __uint_as_float(v & 0xFFFF0000u); }

// ---- pass A: LDS bucket sort of edges by dst>>8 into strided staging ----
__global__ __launch_bounds__(1024, 4)
void bucket_kernel(const int* __restrict__ src, const int* __restrict__ dst,
                   int* __restrict__ bucket_count, int* __restrict__ staged) {
    __shared__ int hist[NBUCK];
    __shared__ int lscan[NBUCK];
    __shared__ int gbase[NBUCK];
    __shared__ int cursor[NBUCK];
    __shared__ int sorted[CHUNK];  // 32 KB
    int tid = threadIdx.x;
    int base = blockIdx.x * CHUNK;
    if (tid < NBUCK) { hist[tid] = 0; cursor[tid] = 0; }
    __syncthreads();
    int d8[8], s8[8];
#pragma unroll
    for (int k = 0; k < 8; k++) {
        int i = base + k * 1024 + tid;
        d8[k] = dst[i];
        s8[k] = src[i];
        atomicAdd(&hist[d8[k] >> 8], 1);
    }
    __syncthreads();
    if (tid < NBUCK) lscan[tid] = hist[tid];
    __syncthreads();
    for (int off = 1; off < NBUCK; off <<= 1) {
        int u = (tid < NBUCK && tid >= off) ? lscan[tid - off] : 0;
        __syncthreads();
        if (tid < NBUCK) lscan[tid] += u;
        __syncthreads();
    }
    if (tid < NBUCK) gbase[tid] = atomicAdd(&bucket_count[tid], hist[tid]);
    __syncthreads();
#pragma unroll
    for (int k = 0; k < 8; k++) {
        int b = d8[k] >> 8;
        int start = lscan[b] - hist[b];
        int p = start + atomicAdd(&cursor[b], 1);
        sorted[p] = ((d8[k] & 255) << 17) | s8[k];
    }
    __syncthreads();
    int wid = tid >> 6, lane = tid & 63;
    int g16 = lane >> 4, k16 = lane & 15;
    for (int b0 = wid * 4; b0 < NBUCK; b0 += 64) {
        int b = b0 + g16;
        int cb = hist[b];
        int lbase = lscan[b] - cb;
        int gb = b * STRIDE + gbase[b];
        for (int k = k16; k < cb; k += 16) staged[gb + k] = sorted[lbase + k];
    }
}

// ---- per-bucket: count + scan + place in one kernel; + prescaled x cast ----
__global__ void build_kernel(const int* __restrict__ bucket_count, const int* __restrict__ staged,
                             int2* __restrict__ rowbounds, float* __restrict__ dinv,
                             int* __restrict__ csr, const float* __restrict__ x,
                             unsigned short* __restrict__ xb) {
    __shared__ int sl[STRIDE];     // 18.4 KB bucket slice
    __shared__ int image[CAP];     // 20.5 KB csr image (src<<6)
    __shared__ int cnt[256];
    __shared__ int scn[256];
    __shared__ int loff[256];
    __shared__ int cursor[256];
    __shared__ int totalS;
    int b = blockIdx.x;
    int tid = threadIdx.x;
    int count = bucket_count[b];
    const int* st = staged + b * STRIDE;
    cnt[tid] = 0;
    cursor[tid] = 0;
    for (int i = tid; i < count; i += 256) sl[i] = st[i];
    __syncthreads();
    for (int i = tid; i < count; i += 256) atomicAdd(&cnt[(sl[i] >> 17) & 255], 1);
    __syncthreads();
    int deg = cnt[tid];
    int degp = (deg + 3) & ~3;  // pad to x4
    scn[tid] = degp;
    __syncthreads();
    for (int off = 1; off < 256; off <<= 1) {
        int u = (tid >= off) ? scn[tid - off] : 0;
        __syncthreads();
        scn[tid] += u;
        __syncthreads();
    }
    int lo = scn[tid] - degp;
    loff[tid] = lo;
    int nbase = (b << 8) + tid;
    int gb = b * CSR_STRIDE;
    rowbounds[nbase] = make_int2(gb + lo, gb + lo + degp);
    float dv = rsqrtf((float)deg + 1.0f);
    dinv[nbase] = dv;
    if (tid == 255) totalS = lo + degp;
    {
        const float* xp = x + nbase * IN_CH;
        unsigned o[8];
#pragma unroll
        for (int k = 0; k < 6; k++) o[k] = pack2bf(dv * xp[2 * k], dv * xp[2 * k + 1]);
        o[6] = 0; o[7] = 0;
        uint4* dstp = (uint4*)(xb + nbase * 16);
        dstp[0] = make_uint4(o[0], o[1], o[2], o[3]);
        dstp[1] = make_uint4(o[4], o[5], o[6], o[7]);
    }
    if (b == 0 && tid < 2)  // zero row N_NODES of xb (pad target)
        ((uint4*)(xb + (size_t)N_NODES * 16))[tid] = make_uint4(0, 0, 0, 0);
    __syncthreads();
    for (int i = tid; i < count; i += 256) {
        int rec = sl[i];
        int s = rec & 0x1FFFF;
        int dq = (rec >> 17) & 255;
        int p = loff[dq] + atomicAdd(&cursor[dq], 1);
        int val = s << 6;  // >>2: x16-row (bf16 x) | >>1: 32B-row byte off (fp8 half-tables)
        if (p < CAP) image[p] = val;
        else csr[gb + p] = val;
    }
    __syncthreads();
    int padval = N_NODES << 6;  // zero row
    for (int p = loff[tid] + deg; p < loff[tid] + degp; p++) {
        if (p < CAP) image[p] = padval;
        else csr[gb + p] = padval;
    }
    __syncthreads();
    int lim = totalS < CAP ? totalS : CAP;
    int* dstp = csr + gb;
    for (int i = tid; i < lim; i += 256) dstp[i] = image[i];
}

// ---- layer-1 aggregation over prescaled x table: wave = 32 nodes ----
__global__ void agg_x_kernel(const int2* __restrict__ rowbounds, const int* __restrict__ csr,
                             const float* __restrict__ dinv,
                             const unsigned short* __restrict__ xb, float* __restrict__ aggx) {
    int tid = threadIdx.x;
    int w = tid >> 6, lane = tid & 63, sub = lane >> 1, p = lane & 1;
    int qoff = 8 * p;
    int node = (blockIdx.x * 4 + w) * 32 + sub;
    int2 rb = rowbounds[node];
    float dn = dinv[node];
    f32x2 a0[4] = {{0, 0}, {0, 0}, {0, 0}, {0, 0}};
    f32x2 a1[4] = {{0, 0}, {0, 0}, {0, 0}, {0, 0}};
    f32x2 a2[4] = {{0, 0}, {0, 0}, {0, 0}, {0, 0}};
    f32x2 a3[4] = {{0, 0}, {0, 0}, {0, 0}, {0, 0}};
    for (int j = rb.x; j < rb.y; j += 4) {  // padded x4: no remainder
        int4 e = *(const int4*)(csr + j);
        uint4 u0 = *(const uint4*)(xb + (e.x >> 2) + qoff);
        uint4 u1 = *(const uint4*)(xb + (e.y >> 2) + qoff);
        uint4 u2 = *(const uint4*)(xb + (e.z >> 2) + qoff);
        uint4 u3 = *(const uint4*)(xb + (e.w >> 2) + qoff);
        a0[0] += (f32x2){bflo(u0.x), bfhi(u0.x)};
        a0[1] += (f32x2){bflo(u0.y), bfhi(u0.y)};
        a0[2] += (f32x2){bflo(u0.z), bfhi(u0.z)};
        a0[3] += (f32x2){bflo(u0.w), bfhi(u0.w)};
        a1[0] += (f32x2){bflo(u1.x), bfhi(u1.x)};
        a1[1] += (f32x2){bflo(u1.y), bfhi(u1.y)};
        a1[2] += (f32x2){bflo(u1.z), bfhi(u1.z)};
        a1[3] += (f32x2){bflo(u1.w), bfhi(u1.w)};
        a2[0] += (f32x2){bflo(u2.x), bfhi(u2.x)};
        a2[1] += (f32x2){bflo(u2.y), bfhi(u2.y)};
        a2[2] += (f32x2){bflo(u2.z), bfhi(u2.z)};
        a2[3] += (f32x2){bflo(u2.w), bfhi(u2.w)};
        a3[0] += (f32x2){bflo(u3.x), bfhi(u3.x)};
        a3[1] += (f32x2){bflo(u3.y), bfhi(u3.y)};
        a3[2] += (f32x2){bflo(u3.z), bfhi(u3.z)};
        a3[3] += (f32x2){bflo(u3.w), bfhi(u3.w)};
    }
    uint4 su = *(const uint4*)(xb + node * 16 + qoff);  // xb' already has dinv_s
    a0[0] += (f32x2){bflo(su.x), bfhi(su.x)};
    a0[1] += (f32x2){bflo(su.y), bfhi(su.y)};
    a0[2] += (f32x2){bflo(su.z), bfhi(su.z)};
    a0[3] += (f32x2){bflo(su.w), bfhi(su.w)};
    f32x2 nd = {dn, dn};
    f32x2 s0 = nd * ((a0[0] + a1[0]) + (a2[0] + a3[0]));
    f32x2 s1 = nd * ((a0[1] + a1[1]) + (a2[1] + a3[1]));
    f32x2 s2 = nd * ((a0[2] + a1[2]) + (a2[2] + a3[2]));
    f32x2 s3 = nd * ((a0[3] + a1[3]) + (a2[3] + a3[3]));
    float4 o0 = make_float4(s0[0], s0[1], s1[0], s1[1]);
    float4 o1 = make_float4(s2[0], s2[1], s3[0], s3[1]);
    *(float4*)(aggx + node * 16 + qoff) = o0;
    *(float4*)(aggx + node * 16 + qoff + 4) = o1;
}

// ---- fused: h1 = relu(aggx@W1+b1) in LDS; dinv*(h1@W2) -> two fp8 half-tables ----
__global__ void w1w2_kernel(const float* __restrict__ aggx, const float* __restrict__ W1,
                            const float* __restrict__ b1, const float* __restrict__ W2,
                            const float* __restrict__ dinv,
                            unsigned char* __restrict__ hBa, unsigned char* __restrict__ hBb) {
    __shared__ float sW1[IN_CH * HID];
    __shared__ float sW2[HID * HID];
    __shared__ float sA[256];
    __shared__ float sh1[16 * HID];
    int tid = threadIdx.x;
    for (int i = tid; i < IN_CH * HID; i += 256) sW1[i] = W1[i];
    for (int i = tid; i < HID * HID; i += 256) sW2[i] = W2[i];
    int node0 = blockIdx.x * 16;
    sA[tid] = aggx[node0 * 16 + tid];
    __syncthreads();
    int nl = tid >> 4, c4 = (tid & 15) * 4;
    float a0 = 0, a1 = 0, a2 = 0, a3 = 0;
#pragma unroll
    for (int k = 0; k < IN_CH; k++) {
        float av = sA[nl * 16 + k];
        const float* w = &sW1[k * HID + c4];
        a0 += av * w[0]; a1 += av * w[1]; a2 += av * w[2]; a3 += av * w[3];
    }
    const float* bb = &b1[c4];
    sh1[nl * HID + c4 + 0] = fmaxf(a0 + bb[0], 0.0f);
    sh1[nl * HID + c4 + 1] = fmaxf(a1 + bb[1], 0.0f);
    sh1[nl * HID + c4 + 2] = fmaxf(a2 + bb[2], 0.0f);
    sh1[nl * HID + c4 + 3] = fmaxf(a3 + bb[3], 0.0f);
    __syncthreads();
    float c0 = 0, c1 = 0, c2 = 0, c3 = 0;
#pragma unroll 8
    for (int k = 0; k < HID; k++) {
        float hv = sh1[nl * HID + k];
        float4 w = *(const float4*)&sW2[k * HID + c4];
        c0 += hv * w.x; c1 += hv * w.y; c2 += hv * w.z; c3 += hv * w.w;
    }
    float dv = dinv[node0 + nl];
    unsigned int packed = (unsigned int)__builtin_amdgcn_cvt_pk_fp8_f32(dv * c0, dv * c1, 0, false);
    packed = (unsigned int)__builtin_amdgcn_cvt_pk_fp8_f32(dv * c2, dv * c3, (int)packed, true);
    unsigned char* base = (c4 < 32) ? hBa : hBb;
    *(unsigned int*)(base + (size_t)(node0 + nl) * 32 + (c4 & 31)) = packed;
    if (blockIdx.x == 0 && tid < 8) {  // zero row N_NODES of both half-tables
        ((unsigned int*)(hBa + (size_t)N_NODES * 32))[tid] = 0;
        ((unsigned int*)(hBb + (size_t)N_NODES * 32))[tid] = 0;
    }
}

// ---- fp8 half-table gather: 4-lane subgroups, 16 nodes/wave, 8 edges in flight ----
__device__ __forceinline__ void add_fp8(f32x2* a, uint2 u) {
    a[0] += __builtin_amdgcn_cvt_pk_f32_fp8((int)u.x, false);
    a[1] += __builtin_amdgcn_cvt_pk_f32_fp8((int)u.x, true);
    a[2] += __builtin_amdgcn_cvt_pk_f32_fp8((int)u.y, false);
    a[3] += __builtin_amdgcn_cvt_pk_f32_fp8((int)u.y, true);
}

__global__ void agg_pool_half_kernel(const int2* __restrict__ rowbounds,
                                     const int* __restrict__ csr,
                                     const float* __restrict__ dinv,
                                     const unsigned char* __restrict__ h,   // half-table, 32 B rows
                                     const float* __restrict__ b2,
                                     const int* __restrict__ batch,
                                     float* __restrict__ pool, float* __restrict__ gcnt,
                                     int chan_off, int do_gcnt) {
    __shared__ float red[64][32];  // 8 KB
    __shared__ int gids[64];
    int tid = threadIdx.x;
    int w = tid >> 6, lane = tid & 63, sub = lane >> 2, q = lane & 3;
    int qoff = 8 * q;  // byte offset within 32 B row = 8 channels
    int nl = w * 16 + sub;
    int node = blockIdx.x * 64 + nl;
    int2 rb = rowbounds[node];
    float dn = dinv[node];
    f32x2 a0[4] = {{0, 0}, {0, 0}, {0, 0}, {0, 0}};
    f32x2 a1[4] = {{0, 0}, {0, 0}, {0, 0}, {0, 0}};
    f32x2 a2[4] = {{0, 0}, {0, 0}, {0, 0}, {0, 0}};
    f32x2 a3[4] = {{0, 0}, {0, 0}, {0, 0}, {0, 0}};
    int j = rb.x;
    for (; j + 8 <= rb.y; j += 8) {  // 8 edges in flight
        int4 ea = *(const int4*)(csr + j);
        int4 eb = *(const int4*)(csr + j + 4);
        uint2 u0 = *(const uint2*)(h + (ea.x >> 1) + qoff);  // s<<6 >>1 = 32B row
        uint2 u1 = *(const uint2*)(h + (ea.y >> 1) + qoff);
        uint2 u2 = *(const uint2*)(h + (ea.z >> 1) + qoff);
        uint2 u3 = *(const uint2*)(h + (ea.w >> 1) + qoff);
        uint2 u4 = *(const uint2*)(h + (eb.x >> 1) + qoff);
        uint2 u5 = *(const uint2*)(h + (eb.y >> 1) + qoff);
        uint2 u6 = *(const uint2*)(h + (eb.z >> 1) + qoff);
        uint2 u7 = *(const uint2*)(h + (eb.w >> 1) + qoff);
        add_fp8(a0, u0); add_fp8(a1, u1); add_fp8(a2, u2); add_fp8(a3, u3);
        add_fp8(a0, u4); add_fp8(a1, u5); add_fp8(a2, u6); add_fp8(a3, u7);
    }
    if (j < rb.y) {  // exactly 4 padded edges remain
        int4 ea = *(const int4*)(csr + j);
        uint2 u0 = *(const uint2*)(h + (ea.x >> 1) + qoff);
        uint2 u1 = *(const uint2*)(h + (ea.y >> 1) + qoff);
        uint2 u2 = *(const uint2*)(h + (ea.z >> 1) + qoff);
        uint2 u3 = *(const uint2*)(h + (ea.w >> 1) + qoff);
        add_fp8(a0, u0); add_fp8(a1, u1); add_fp8(a2, u2); add_fp8(a3, u3);
    }
    uint2 su = *(const uint2*)(h + (size_t)node * 32 + qoff);  // prescaled self row
    add_fp8(a0, su);
    f32x2 s0 = (a0[0] + a1[0]) + (a2[0] + a3[0]);
    f32x2 s1 = (a0[1] + a1[1]) + (a2[1] + a3[1]);
    f32x2 s2 = (a0[2] + a1[2]) + (a2[2] + a3[2]);
    f32x2 s3 = (a0[3] + a1[3]) + (a2[3] + a3[3]);
    float4 bb0 = *(const float4*)&b2[chan_off + qoff];
    float4 bb1 = *(const float4*)&b2[chan_off + qoff + 4];
    float4 v0, v1;
    v0.x = fmaxf(dn * s0[0] + bb0.x, 0.0f);
    v0.y = fmaxf(dn * s0[1] + bb0.y, 0.0f);
    v0.z = fmaxf(dn * s1[0] + bb0.z, 0.0f);
    v0.w = fmaxf(dn * s1[1] + bb0.w, 0.0f);
    v1.x = fmaxf(dn * s2[0] + bb1.x, 0.0f);
    v1.y = fmaxf(dn * s2[1] + bb1.y, 0.0f);
    v1.z = fmaxf(dn * s3[0] + bb1.z, 0.0f);
    v1.w = fmaxf(dn * s3[1] + bb1.w, 0.0f);
    *(float4*)&red[nl][qoff] = v0;
    *(float4*)&red[nl][qoff + 4] = v1;
    if (q == 0) gids[nl] = batch[node];
    __syncthreads();
    if (tid < 64) {  // wave 0: run-length reduce; lanes 0-31 nodes 0-31, 32-63 nodes 32-63
        int half = tid >> 5, c = tid & 31;
        int n0 = half * 32;
        float acc = 0.0f;
        int cur = gids[n0], cnt = 0;
        for (int n = n0; n < n0 + 32; n++) {
            int g = gids[n];
            if (g != cur) {
                atomicAdd(&pool[cur * HID + chan_off + c], acc);
                if (do_gcnt && c == 0) atomicAdd(&gcnt[cur], (float)cnt);
                acc = 0.0f; cnt = 0; cur = g;
            }
            acc += red[n][c];
            cnt++;
        }
        atomicAdd(&pool[cur * HID + chan_off + c], acc);
        if (do_gcnt && c == 0) atomicAdd(&gcnt[cur], (float)cnt);
    }
}

// ---- final: out = sigmoid((pool/cnt) @ Wfc + bfc) ----
__global__ void final_kernel(const float* __restrict__ pool, const float* __restrict__ gcnt,
                             const float* __restrict__ Wfc, const float* __restrict__ bfc,
                             float* __restrict__ out) {
    int idx = blockIdx.x * 256 + threadIdx.x;
    if (idx >= N_GRAPHS * OUT_CH) return;
    int g = idx >> 2, o = idx & 3;
    float inv = 1.0f / fmaxf(gcnt[g], 1.0f);
    float acc = bfc[o];
#pragma unroll
    for (int k = 0; k < HID; k++) acc += pool[g * HID + k] * inv * Wfc[k * OUT_CH + o];
    out[idx] = 1.0f / (1.0f + expf(-acc));
}

extern "C" void kernel_launch(void* const* d_in, const int* in_sizes, int n_in,
                              void* d_out, int out_size, void* d_ws, size_t ws_size,
                              hipStream_t stream) {
    const float* x   = (const float*)d_in[0];
    const int* eidx  = (const int*)d_in[1];
    const int* batch = (const int*)d_in[2];
    const float* W1  = (const float*)d_in[3];
    const float* b1  = (const float*)d_in[4];
    const float* W2  = (const float*)d_in[5];
    const float* b2  = (const float*)d_in[6];
    const float* Wfc = (const float*)d_in[7];
    const float* bfc = (const float*)d_in[8];
    float* out = (float*)d_out;

    const int* src = eidx;
    const int* dst = eidx + N_EDGES;

    // workspace layout (~45 MB)
    unsigned char* hBa = (unsigned char*)d_ws;                 // 4 MB fp8 ch 0-31 (+zero row)
    unsigned char* hBb = hBa + (size_t)(N_NODES + 1) * 32;     // 4 MB fp8 ch 32-63 (+zero row)
    int*   csr    = (int*)(hBb + (size_t)(N_NODES + 1) * 32);  // 10.5 MB src<<6
    int*   staged = csr + (size_t)NBUCK * CSR_STRIDE;          // 9.4 MB bucket-strided
    float* dinv   = (float*)(staged + (size_t)NBUCK * STRIDE); // 512 KB
    int2*  rowbounds = (int2*)(dinv + N_NODES);                // 1 MB
    int*   bucket_count = (int*)(rowbounds + N_NODES);         // 2 KB
    float* pool   = (float*)(bucket_count + NBUCK);            // 512 KB
    float* gcnt   = pool + N_GRAPHS * HID;                     // 8 KB
    unsigned short* xb = (unsigned short*)(gcnt + N_GRAPHS);   // 4 MB bf16 [N+1,16]
    float* aggx   = (float*)(xb + (size_t)(N_NODES + 1) * 16); // 8 MB fp32 [N,16]

    hipMemsetAsync(bucket_count, 0, (size_t)NBUCK * 4, stream);
    hipMemsetAsync(pool, 0, (size_t)(N_GRAPHS * HID + N_GRAPHS) * 4, stream);

    // CSR build: bucket sort -> fused count/scan/place (+prescaled xcast)
    bucket_kernel<<<N_EDGES / CHUNK, 1024, 0, stream>>>(src, dst, bucket_count, staged);
    build_kernel<<<NBUCK, 256, 0, stream>>>(bucket_count, staged, rowbounds, dinv, csr, x, xb);

    // layer 1: agg(x') then fused W1+W2 (h1 LDS-only) -> two fp8 half-tables
    agg_x_kernel<<<N_NODES / 128, 256, 0, stream>>>(rowbounds, csr, dinv, xb, aggx);
    w1w2_kernel<<<N_NODES / 16, 256, 0, stream>>>(aggx, W1, b1, W2, dinv, hBa, hBb);

    // layer 2: two L2-resident half-channel gather passes (+pool)
    agg_pool_half_kernel<<<N_NODES / 64, 256, 0, stream>>>(rowbounds, csr, dinv, hBa, b2,
                                                           batch, pool, gcnt, 0, 1);
    agg_pool_half_kernel<<<N_NODES / 64, 256, 0, stream>>>(rowbounds, csr, dinv, hBb, b2,
                                                           batch, pool, gcnt, 32, 0);

    // head
    final_kernel<<<(N_GRAPHS * OUT_CH + 255) / 256, 256, 0, stream>>>(pool, gcnt, Wfc, bfc, out);
}

// Round 18
// 192.000 us; speedup vs baseline: 1.0988x; 1.0988x over previous
//
#include <hip/hip_runtime.h>
#include <hip/hip_bf16.h>

// GCN. CSR via 2-pass LDS bucket sort; tables prescaled by dinv[src] (csr = 4 B/edge).
// Layer 1: agg over 4 MB bf16 x-table (L2-resident). Layer 2: single 8 MB fp8
// table (R17 showed splitting it doubles per-edge line requests — the actual
// limiter; a 32 B request still pulls a 64 B line). h1 LDS-only; w1w2 matmul
// register-tiled 4 nodes x 4 ch per thread over transposed h1 (R17 counters:
// old w1w2 was LDS-throughput-bound at 46 us, 2 LDS reads per 4 FMAs).

#define N_NODES 131072
#define N_EDGES 2097152
#define N_GRAPHS 2048
#define IN_CH 12
#define HID 64
#define OUT_CH 4
#define NBUCK 512          // buckets of 256 dst nodes
#define CHUNK 8192         // edges per bucket_kernel block
#define STRIDE 4608        // staging capacity per bucket (mean 4096, sd 64)
#define CSR_STRIDE 5120    // csr capacity per bucket (padded mean ~4500)
#define CAP 5120           // build_kernel LDS image capacity (20.5 KB, int)

typedef float f32x2 __attribute__((ext_vector_type(2)));

__device__ __forceinline__ unsigned short f2bf(float f) {
    unsigned u = __float_as_uint(f);
    return (unsigned short)((u + 0x7fffu + ((u >> 16) & 1u)) >> 16);  // RNE
}
__device__ __forceinline__ unsigned pack2bf(float lo, float hi) {
    return (unsigned)f2bf(lo) | ((unsigned)f2bf(hi) << 16);
}
__device__ __forceinline__ float bflo(unsigned v) { return __uint_as_float(v << 16); }
__device__ __forceinline__ float bfhi(unsigned v) { return __uint_as_float(v & 0xFFFF0000u); }

// ---- pass A: LDS bucket sort of edges by dst>>8 into strided staging ----
__global__ __launch_bounds__(1024, 4)
void bucket_kernel(const int* __restrict__ src, const int* __restrict__ dst,
                   int* __restrict__ bucket_count, int* __restrict__ staged) {
    __shared__ int hist[NBUCK];
    __shared__ int lscan[NBUCK];
    __shared__ int gbase[NBUCK];
    __shared__ int cursor[NBUCK];
    __shared__ int sorted[CHUNK];  // 32 KB
    int tid = threadIdx.x;
    int base = blockIdx.x * CHUNK;
    if (tid < NBUCK) { hist[tid] = 0; cursor[tid] = 0; }
    __syncthreads();
    int d8[8], s8[8];
#pragma unroll
    for (int k = 0; k < 8; k++) {
        int i = base + k * 1024 + tid;
        d8[k] = dst[i];
        s8[k] = src[i];
        atomicAdd(&hist[d8[k] >> 8], 1);
    }
    __syncthreads();
    if (tid < NBUCK) lscan[tid] = hist[tid];
    __syncthreads();
    for (int off = 1; off < NBUCK; off <<= 1) {
        int u = (tid < NBUCK && tid >= off) ? lscan[tid - off] : 0;
        __syncthreads();
        if (tid < NBUCK) lscan[tid] += u;
        __syncthreads();
    }
    if (tid < NBUCK) gbase[tid] = atomicAdd(&bucket_count[tid], hist[tid]);
    __syncthreads();
#pragma unroll
    for (int k = 0; k < 8; k++) {
        int b = d8[k] >> 8;
        int start = lscan[b] - hist[b];
        int p = start + atomicAdd(&cursor[b], 1);
        sorted[p] = ((d8[k] & 255) << 17) | s8[k];
    }
    __syncthreads();
    int wid = tid >> 6, lane = tid & 63;
    int g16 = lane >> 4, k16 = lane & 15;
    for (int b0 = wid * 4; b0 < NBUCK; b0 += 64) {
        int b = b0 + g16;
        int cb = hist[b];
        int lbase = lscan[b] - cb;
        int gb = b * STRIDE + gbase[b];
        for (int k = k16; k < cb; k += 16) staged[gb + k] = sorted[lbase + k];
    }
}

// ---- per-bucket: count + scan + place in one kernel; + prescaled x cast ----
__global__ void build_kernel(const int* __restrict__ bucket_count, const int* __restrict__ staged,
                             int2* __restrict__ rowbounds, float* __restrict__ dinv,
                             int* __restrict__ csr, const float* __restrict__ x,
                             unsigned short* __restrict__ xb) {
    __shared__ int sl[STRIDE];     // 18.4 KB bucket slice
    __shared__ int image[CAP];     // 20.5 KB csr image (src<<6)
    __shared__ int cnt[256];
    __shared__ int scn[256];
    __shared__ int loff[256];
    __shared__ int cursor[256];
    __shared__ int totalS;
    int b = blockIdx.x;
    int tid = threadIdx.x;
    int count = bucket_count[b];
    const int* st = staged + b * STRIDE;
    cnt[tid] = 0;
    cursor[tid] = 0;
    for (int i = tid; i < count; i += 256) sl[i] = st[i];
    __syncthreads();
    for (int i = tid; i < count; i += 256) atomicAdd(&cnt[(sl[i] >> 17) & 255], 1);
    __syncthreads();
    int deg = cnt[tid];
    int degp = (deg + 3) & ~3;  // pad to x4
    scn[tid] = degp;
    __syncthreads();
    for (int off = 1; off < 256; off <<= 1) {
        int u = (tid >= off) ? scn[tid - off] : 0;
        __syncthreads();
        scn[tid] += u;
        __syncthreads();
    }
    int lo = scn[tid] - degp;
    loff[tid] = lo;
    int nbase = (b << 8) + tid;
    int gb = b * CSR_STRIDE;
    rowbounds[nbase] = make_int2(gb + lo, gb + lo + degp);
    float dv = rsqrtf((float)deg + 1.0f);
    dinv[nbase] = dv;
    if (tid == 255) totalS = lo + degp;
    {
        const float* xp = x + nbase * IN_CH;
        unsigned o[8];
#pragma unroll
        for (int k = 0; k < 6; k++) o[k] = pack2bf(dv * xp[2 * k], dv * xp[2 * k + 1]);
        o[6] = 0; o[7] = 0;
        uint4* dstp = (uint4*)(xb + nbase * 16);
        dstp[0] = make_uint4(o[0], o[1], o[2], o[3]);
        dstp[1] = make_uint4(o[4], o[5], o[6], o[7]);
    }
    if (b == 0 && tid < 2)  // zero row N_NODES of xb (pad target)
        ((uint4*)(xb + (size_t)N_NODES * 16))[tid] = make_uint4(0, 0, 0, 0);
    __syncthreads();
    for (int i = tid; i < count; i += 256) {
        int rec = sl[i];
        int s = rec & 0x1FFFF;
        int dq = (rec >> 17) & 255;
        int p = loff[dq] + atomicAdd(&cursor[dq], 1);
        int val = s << 6;  // byte off into 64B fp8 row | >>2: x16 bf16 row
        if (p < CAP) image[p] = val;
        else csr[gb + p] = val;
    }
    __syncthreads();
    int padval = N_NODES << 6;  // zero row
    for (int p = loff[tid] + deg; p < loff[tid] + degp; p++) {
        if (p < CAP) image[p] = padval;
        else csr[gb + p] = padval;
    }
    __syncthreads();
    int lim = totalS < CAP ? totalS : CAP;
    int* dstp = csr + gb;
    for (int i = tid; i < lim; i += 256) dstp[i] = image[i];
}

// ---- layer-1 aggregation over prescaled x table: wave = 32 nodes ----
__global__ void agg_x_kernel(const int2* __restrict__ rowbounds, const int* __restrict__ csr,
                             const float* __restrict__ dinv,
                             const unsigned short* __restrict__ xb, float* __restrict__ aggx) {
    int tid = threadIdx.x;
    int w = tid >> 6, lane = tid & 63, sub = lane >> 1, p = lane & 1;
    int qoff = 8 * p;
    int node = (blockIdx.x * 4 + w) * 32 + sub;
    int2 rb = rowbounds[node];
    float dn = dinv[node];
    f32x2 a0[4] = {{0, 0}, {0, 0}, {0, 0}, {0, 0}};
    f32x2 a1[4] = {{0, 0}, {0, 0}, {0, 0}, {0, 0}};
    f32x2 a2[4] = {{0, 0}, {0, 0}, {0, 0}, {0, 0}};
    f32x2 a3[4] = {{0, 0}, {0, 0}, {0, 0}, {0, 0}};
    for (int j = rb.x; j < rb.y; j += 4) {  // padded x4: no remainder
        int4 e = *(const int4*)(csr + j);
        uint4 u0 = *(const uint4*)(xb + (e.x >> 2) + qoff);
        uint4 u1 = *(const uint4*)(xb + (e.y >> 2) + qoff);
        uint4 u2 = *(const uint4*)(xb + (e.z >> 2) + qoff);
        uint4 u3 = *(const uint4*)(xb + (e.w >> 2) + qoff);
        a0[0] += (f32x2){bflo(u0.x), bfhi(u0.x)};
        a0[1] += (f32x2){bflo(u0.y), bfhi(u0.y)};
        a0[2] += (f32x2){bflo(u0.z), bfhi(u0.z)};
        a0[3] += (f32x2){bflo(u0.w), bfhi(u0.w)};
        a1[0] += (f32x2){bflo(u1.x), bfhi(u1.x)};
        a1[1] += (f32x2){bflo(u1.y), bfhi(u1.y)};
        a1[2] += (f32x2){bflo(u1.z), bfhi(u1.z)};
        a1[3] += (f32x2){bflo(u1.w), bfhi(u1.w)};
        a2[0] += (f32x2){bflo(u2.x), bfhi(u2.x)};
        a2[1] += (f32x2){bflo(u2.y), bfhi(u2.y)};
        a2[2] += (f32x2){bflo(u2.z), bfhi(u2.z)};
        a2[3] += (f32x2){bflo(u2.w), bfhi(u2.w)};
        a3[0] += (f32x2){bflo(u3.x), bfhi(u3.x)};
        a3[1] += (f32x2){bflo(u3.y), bfhi(u3.y)};
        a3[2] += (f32x2){bflo(u3.z), bfhi(u3.z)};
        a3[3] += (f32x2){bflo(u3.w), bfhi(u3.w)};
    }
    uint4 su = *(const uint4*)(xb + node * 16 + qoff);  // xb' already has dinv_s
    a0[0] += (f32x2){bflo(su.x), bfhi(su.x)};
    a0[1] += (f32x2){bflo(su.y), bfhi(su.y)};
    a0[2] += (f32x2){bflo(su.z), bfhi(su.z)};
    a0[3] += (f32x2){bflo(su.w), bfhi(su.w)};
    f32x2 nd = {dn, dn};
    f32x2 s0 = nd * ((a0[0] + a1[0]) + (a2[0] + a3[0]));
    f32x2 s1 = nd * ((a0[1] + a1[1]) + (a2[1] + a3[1]));
    f32x2 s2 = nd * ((a0[2] + a1[2]) + (a2[2] + a3[2]));
    f32x2 s3 = nd * ((a0[3] + a1[3]) + (a2[3] + a3[3]));
    float4 o0 = make_float4(s0[0], s0[1], s1[0], s1[1]);
    float4 o1 = make_float4(s2[0], s2[1], s3[0], s3[1]);
    *(float4*)(aggx + node * 16 + qoff) = o0;
    *(float4*)(aggx + node * 16 + qoff + 4) = o1;
}

// ---- fused w1+w2, register-tiled: 64 nodes/block; h1 transposed in LDS ----
__global__ void w1w2_kernel(const float* __restrict__ aggx, const float* __restrict__ W1,
                            const float* __restrict__ b1, const float* __restrict__ W2,
                            const float* __restrict__ dinv, unsigned int* __restrict__ hout) {
    __shared__ float sW1[IN_CH * HID];     // 3 KB
    __shared__ float sW2[HID * HID];       // 16 KB
    __shared__ float sA[64 * 17];          // 4.25 KB (padded pitch 17)
    __shared__ float sh1t[HID * 65];       // 16.25 KB: h1^T [ch][node], pitch 65
    int tid = threadIdx.x;
    for (int i = tid; i < IN_CH * HID; i += 256) sW1[i] = W1[i];
    for (int i = tid; i < HID * HID; i += 256) sW2[i] = W2[i];
    int node0 = blockIdx.x * 64;
    {   // load 64 aggx rows (16 fp32 each), store padded
        float4 v = *(const float4*)(aggx + node0 * 16 + tid * 4);
        int n = tid >> 2, part = (tid & 3) * 4;
        sA[n * 17 + part + 0] = v.x;
        sA[n * 17 + part + 1] = v.y;
        sA[n * 17 + part + 2] = v.z;
        sA[n * 17 + part + 3] = v.w;
    }
    __syncthreads();
    // phase 1 (W1): wave w computes 16-node x 64-ch tile; lane = channel
    int w = tid >> 6, c = tid & 63;
    float bc = b1[c];
#pragma unroll
    for (int it = 0; it < 4; it++) {
        int n0 = w * 16 + it * 4;
        float a0 = bc, a1 = bc, a2 = bc, a3 = bc;
#pragma unroll
        for (int k = 0; k < IN_CH; k++) {
            float wv = sW1[k * HID + c];
            a0 += sA[(n0 + 0) * 17 + k] * wv;  // sA reads broadcast per wave
            a1 += sA[(n0 + 1) * 17 + k] * wv;
            a2 += sA[(n0 + 2) * 17 + k] * wv;
            a3 += sA[(n0 + 3) * 17 + k] * wv;
        }
        float4 o = make_float4(fmaxf(a0, 0.0f), fmaxf(a1, 0.0f),
                               fmaxf(a2, 0.0f), fmaxf(a3, 0.0f));
        *(float4*)&sh1t[c * 65 + n0] = o;  // transposed: [ch][node]
    }
    __syncthreads();
    // phase 2 (W2): thread = 4 nodes x 4 ch; per k: 2 x b128 for 16 FMA
    int nq = tid >> 4, c4 = (tid & 15) * 4;
    float4 a0 = {0, 0, 0, 0}, a1 = {0, 0, 0, 0}, a2 = {0, 0, 0, 0}, a3 = {0, 0, 0, 0};
#pragma unroll 4
    for (int k = 0; k < HID; k++) {
        float4 wv = *(const float4*)&sW2[k * HID + c4];
        float4 hv = *(const float4*)&sh1t[k * 65 + nq * 4];  // 4 nodes' h1[k]
        a0.x += hv.x * wv.x; a0.y += hv.x * wv.y; a0.z += hv.x * wv.z; a0.w += hv.x * wv.w;
        a1.x += hv.y * wv.x; a1.y += hv.y * wv.y; a1.z += hv.y * wv.z; a1.w += hv.y * wv.w;
        a2.x += hv.z * wv.x; a2.y += hv.z * wv.y; a2.z += hv.z * wv.z; a2.w += hv.z * wv.w;
        a3.x += hv.w * wv.x; a3.y += hv.w * wv.y; a3.z += hv.w * wv.z; a3.w += hv.w * wv.w;
    }
    int nb = node0 + nq * 4;
    float dv0 = dinv[nb + 0], dv1 = dinv[nb + 1], dv2 = dinv[nb + 2], dv3 = dinv[nb + 3];
    unsigned int p0 = (unsigned int)__builtin_amdgcn_cvt_pk_fp8_f32(dv0 * a0.x, dv0 * a0.y, 0, false);
    p0 = (unsigned int)__builtin_amdgcn_cvt_pk_fp8_f32(dv0 * a0.z, dv0 * a0.w, (int)p0, true);
    unsigned int p1 = (unsigned int)__builtin_amdgcn_cvt_pk_fp8_f32(dv1 * a1.x, dv1 * a1.y, 0, false);
    p1 = (unsigned int)__builtin_amdgcn_cvt_pk_fp8_f32(dv1 * a1.z, dv1 * a1.w, (int)p1, true);
    unsigned int p2 = (unsigned int)__builtin_amdgcn_cvt_pk_fp8_f32(dv2 * a2.x, dv2 * a2.y, 0, false);
    p2 = (unsigned int)__builtin_amdgcn_cvt_pk_fp8_f32(dv2 * a2.z, dv2 * a2.w, (int)p2, true);
    unsigned int p3 = (unsigned int)__builtin_amdgcn_cvt_pk_fp8_f32(dv3 * a3.x, dv3 * a3.y, 0, false);
    p3 = (unsigned int)__builtin_amdgcn_cvt_pk_fp8_f32(dv3 * a3.z, dv3 * a3.w, (int)p3, true);
    int cl = c4 >> 2;
    hout[(nb + 0) * 16 + cl] = p0;   // per-instruction: 64B runs, fully coalesced
    hout[(nb + 1) * 16 + cl] = p1;
    hout[(nb + 2) * 16 + cl] = p2;
    hout[(nb + 3) * 16 + cl] = p3;
    if (blockIdx.x == 0 && tid < 16)  // zero row N_NODES (pad target)
        hout[(size_t)N_NODES * 16 + tid] = 0;
}

// ---- layer-2 fp8 gather body: no per-edge norm; 8 edges in flight ----
__device__ __forceinline__ void add_fp8(f32x2* a, uint2 u) {
    a[0] += __builtin_amdgcn_cvt_pk_f32_fp8((int)u.x, false);
    a[1] += __builtin_amdgcn_cvt_pk_f32_fp8((int)u.x, true);
    a[2] += __builtin_amdgcn_cvt_pk_f32_fp8((int)u.y, false);
    a[3] += __builtin_amdgcn_cvt_pk_f32_fp8((int)u.y, true);
}

__device__ __forceinline__ void agg_body(int beg, int end, const int* __restrict__ csr,
                                         const unsigned char* __restrict__ h,
                                         int qoff, float* r) {
    f32x2 a0[4] = {{0, 0}, {0, 0}, {0, 0}, {0, 0}};
    f32x2 a1[4] = {{0, 0}, {0, 0}, {0, 0}, {0, 0}};
    f32x2 a2[4] = {{0, 0}, {0, 0}, {0, 0}, {0, 0}};
    f32x2 a3[4] = {{0, 0}, {0, 0}, {0, 0}, {0, 0}};
    int j = beg;
    for (; j + 8 <= end; j += 8) {  // 8 edges in flight
        int4 ea = *(const int4*)(csr + j);
        int4 eb = *(const int4*)(csr + j + 4);
        uint2 u0 = *(const uint2*)(h + ea.x + qoff);
        uint2 u1 = *(const uint2*)(h + ea.y + qoff);
        uint2 u2 = *(const uint2*)(h + ea.z + qoff);
        uint2 u3 = *(const uint2*)(h + ea.w + qoff);
        uint2 u4 = *(const uint2*)(h + eb.x + qoff);
        uint2 u5 = *(const uint2*)(h + eb.y + qoff);
        uint2 u6 = *(const uint2*)(h + eb.z + qoff);
        uint2 u7 = *(const uint2*)(h + eb.w + qoff);
        add_fp8(a0, u0); add_fp8(a1, u1); add_fp8(a2, u2); add_fp8(a3, u3);
        add_fp8(a0, u4); add_fp8(a1, u5); add_fp8(a2, u6); add_fp8(a3, u7);
    }
    if (j < end) {  // exactly 4 padded edges remain
        int4 ea = *(const int4*)(csr + j);
        uint2 u0 = *(const uint2*)(h + ea.x + qoff);
        uint2 u1 = *(const uint2*)(h + ea.y + qoff);
        uint2 u2 = *(const uint2*)(h + ea.z + qoff);
        uint2 u3 = *(const uint2*)(h + ea.w + qoff);
        add_fp8(a0, u0); add_fp8(a1, u1); add_fp8(a2, u2); add_fp8(a3, u3);
    }
#pragma unroll
    for (int k = 0; k < 4; k++) {
        f32x2 s = (a0[k] + a1[k]) + (a2[k] + a3[k]);
        r[2 * k] = s[0];
        r[2 * k + 1] = s[1];
    }
}

// ---- layer-2 gather-aggregate + relu + fused mean-pool (run-length flush) ----
__global__ void agg_pool_kernel(const int2* __restrict__ rowbounds, const int* __restrict__ csr,
                                const float* __restrict__ dinv,
                                const unsigned char* __restrict__ h,
                                const float* __restrict__ b, const int* __restrict__ batch,
                                float* __restrict__ pool, float* __restrict__ gcnt) {
    __shared__ float red[32][HID];  // 8 KB
    __shared__ int gids[32];
    int tid = threadIdx.x;
    int w = tid >> 6, lane = tid & 63, sub = lane >> 3, q = lane & 7;
    int qoff = 8 * q;
    int node = (blockIdx.x * 4 + w) * 8 + sub;
    int2 rb = rowbounds[node];
    float dn = dinv[node];
    float r[8];
    agg_body(rb.x, rb.y, csr, h, qoff, r);
    uint2 su = *(const uint2*)(h + node * HID + qoff);  // hB' already has dinv_s
    f32x2 s0 = __builtin_amdgcn_cvt_pk_f32_fp8((int)su.x, false);
    f32x2 s1 = __builtin_amdgcn_cvt_pk_f32_fp8((int)su.x, true);
    f32x2 s2 = __builtin_amdgcn_cvt_pk_f32_fp8((int)su.y, false);
    f32x2 s3 = __builtin_amdgcn_cvt_pk_f32_fp8((int)su.y, true);
    float4 b0 = *(const float4*)&b[qoff];
    float4 b1 = *(const float4*)&b[qoff + 4];
    float4 v0, v1;
    v0.x = fmaxf(dn * (r[0] + s0[0]) + b0.x, 0.0f);
    v0.y = fmaxf(dn * (r[1] + s0[1]) + b0.y, 0.0f);
    v0.z = fmaxf(dn * (r[2] + s1[0]) + b0.z, 0.0f);
    v0.w = fmaxf(dn * (r[3] + s1[1]) + b0.w, 0.0f);
    v1.x = fmaxf(dn * (r[4] + s2[0]) + b1.x, 0.0f);
    v1.y = fmaxf(dn * (r[5] + s2[1]) + b1.y, 0.0f);
    v1.z = fmaxf(dn * (r[6] + s3[0]) + b1.z, 0.0f);
    v1.w = fmaxf(dn * (r[7] + s3[1]) + b1.w, 0.0f);
    int nl = w * 8 + sub;
    *(float4*)&red[nl][qoff] = v0;
    *(float4*)&red[nl][qoff + 4] = v1;
    if (q == 0) gids[nl] = batch[node];
    __syncthreads();
    if (tid < 64) {  // wave 0: run-length reduce 32 nodes (batch sorted)
        int c = tid;
        float acc = 0.0f;
        int cur = gids[0], cnt = 0;
        for (int n = 0; n < 32; n++) {
            int g = gids[n];
            if (g != cur) {
                atomicAdd(&pool[cur * HID + c], acc);
                if (c == 0) atomicAdd(&gcnt[cur], (float)cnt);
                acc = 0.0f; cnt = 0; cur = g;
            }
            acc += red[n][c];
            cnt++;
        }
        atomicAdd(&pool[cur * HID + c], acc);
        if (c == 0) atomicAdd(&gcnt[cur], (float)cnt);
    }
}

// ---- final: out = sigmoid((pool/cnt) @ Wfc + bfc) ----
__global__ void final_kernel(const float* __restrict__ pool, const float* __restrict__ gcnt,
                             const float* __restrict__ Wfc, const float* __restrict__ bfc,
                             float* __restrict__ out) {
    int idx = blockIdx.x * 256 + threadIdx.x;
    if (idx >= N_GRAPHS * OUT_CH) return;
    int g = idx >> 2, o = idx & 3;
    float inv = 1.0f / fmaxf(gcnt[g], 1.0f);
    float acc = bfc[o];
#pragma unroll
    for (int k = 0; k < HID; k++) acc += pool[g * HID + k] * inv * Wfc[k * OUT_CH + o];
    out[idx] = 1.0f / (1.0f + expf(-acc));
}

extern "C" void kernel_launch(void* const* d_in, const int* in_sizes, int n_in,
                              void* d_out, int out_size, void* d_ws, size_t ws_size,
                              hipStream_t stream) {
    const float* x   = (const float*)d_in[0];
    const int* eidx  = (const int*)d_in[1];
    const int* batch = (const int*)d_in[2];
    const float* W1  = (const float*)d_in[3];
    const float* b1  = (const float*)d_in[4];
    const float* W2  = (const float*)d_in[5];
    const float* b2  = (const float*)d_in[6];
    const float* Wfc = (const float*)d_in[7];
    const float* bfc = (const float*)d_in[8];
    float* out = (float*)d_out;

    const int* src = eidx;
    const int* dst = eidx + N_EDGES;

    // workspace layout (~45 MB)
    unsigned char* hB = (unsigned char*)d_ws;                 // 8 MB fp8 (+1 zero row)
    int*   csr    = (int*)(hB + (size_t)(N_NODES + 1) * HID); // 10.5 MB src<<6
    int*   staged = csr + (size_t)NBUCK * CSR_STRIDE;         // 9.4 MB bucket-strided
    float* dinv   = (float*)(staged + (size_t)NBUCK * STRIDE); // 512 KB
    int2*  rowbounds = (int2*)(dinv + N_NODES);               // 1 MB
    int*   bucket_count = (int*)(rowbounds + N_NODES);        // 2 KB
    float* pool   = (float*)(bucket_count + NBUCK);           // 512 KB
    float* gcnt   = pool + N_GRAPHS * HID;                    // 8 KB
    unsigned short* xb = (unsigned short*)(gcnt + N_GRAPHS);  // 4 MB bf16 [N+1,16]
    float* aggx   = (float*)(xb + (size_t)(N_NODES + 1) * 16); // 8 MB fp32 [N,16]

    hipMemsetAsync(bucket_count, 0, (size_t)NBUCK * 4, stream);
    hipMemsetAsync(pool, 0, (size_t)(N_GRAPHS * HID + N_GRAPHS) * 4, stream);

    // CSR build: bucket sort -> fused count/scan/place (+prescaled xcast)
    bucket_kernel<<<N_EDGES / CHUNK, 1024, 0, stream>>>(src, dst, bucket_count, staged);
    build_kernel<<<NBUCK, 256, 0, stream>>>(bucket_count, staged, rowbounds, dinv, csr, x, xb);

    // layer 1: agg(x') then fused register-tiled W1+W2 (h1 LDS-only) -> fp8 hB'
    agg_x_kernel<<<N_NODES / 128, 256, 0, stream>>>(rowbounds, csr, dinv, xb, aggx);
    w1w2_kernel<<<N_NODES / 64, 256, 0, stream>>>(aggx, W1, b1, W2, dinv, (unsigned int*)hB);

    // layer 2: gather + pool
    agg_pool_kernel<<<N_NODES / 32, 256, 0, stream>>>(rowbounds, csr, dinv, hB, b2, batch,
                                                      pool, gcnt);

    // head
    final_kernel<<<(N_GRAPHS * OUT_CH + 255) / 256, 256, 0, stream>>>(pool, gcnt, Wfc, bfc, out);
}